// Round 1
// baseline (106.550 us; speedup 1.0000x reference)
//
#include <hip/hip_runtime.h>
#include <stdint.h>

// ---------------- types ----------------
using f32x4  = __attribute__((ext_vector_type(4))) float;
using short8 = __attribute__((ext_vector_type(8))) short;

#define MFMA(a, b, c) __builtin_amdgcn_mfma_f32_16x16x32_bf16((a), (b), (c), 0, 0, 0)

#define GLOBAL_AS __attribute__((address_space(1)))
#define LDS_AS    __attribute__((address_space(3)))

#define XDIM 256
#define FDIM 512
#define EPS  1e-6f

// ---- workspace layout (bytes) ----
#define QT_OFF    0u          // [512][256] bf16 = 262144
#define KT_OFF    262144u
#define VT_OFF    524288u
#define CTXT_OFF  786432u     // [32][64 e][64 d] bf16 = 262144
#define PART_OFF  1048576u    // [1024][64 d][64 e] f32 = 16 MB
// total = 17825792 bytes

// round-to-nearest-even f32 -> bf16 bits
static __device__ __forceinline__ unsigned short f2bf(float f) {
  unsigned u = __float_as_uint(f);
  unsigned r = u + 0x7FFFu + ((u >> 16) & 1u);
  return (unsigned short)(r >> 16);
}

static __device__ __forceinline__ void async_copy16(const void* g, void* l) {
  __builtin_amdgcn_global_load_lds((GLOBAL_AS const void*)g, (LDS_AS void*)l, 16, 0, 0);
}

// Stage one [256 rows x 64 k] bf16 panel of Wt (row stride 256 bf16 = 512 B) into
// linear LDS [256][128B], XOR-preswizzling the SOURCE chunk so that reads at
// byte = row*128 + (off ^ ((row&7)<<4)) are bank-conflict-free.
// Wave w covers panel rows [w*64, w*64+64).
static __device__ __forceinline__ void stage_wpanel(const unsigned short* wt_panel, int ks,
                                                    int w, int lane, char* Blds) {
  const int cs = ((lane & 7) ^ ((lane >> 3) & 7)) << 4;  // swizzled source chunk byte
  const char* gbase = (const char*)wt_panel + (size_t)ks * 128 + cs;
#pragma unroll
  for (int i = 0; i < 8; ++i) {
    const int frow = w * 64 + i * 8 + (lane >> 3);
    async_copy16(gbase + (size_t)frow * 512, Blds + (size_t)(w * 64 + i * 8) * 128);
  }
}

// Stage A tile: 64 rows x 64 f32 -> bf16 LDS [64][72] (144 B rows, padded: 2-way max)
static __device__ __forceinline__ void stage_a(const float* a_rows, int ks, int tid, char* Alds) {
  const int r = tid >> 2, cq = tid & 3;
  const float* s = a_rows + (size_t)r * XDIM + ks * 64 + cq * 16;
  float4 f0 = *(const float4*)(s);
  float4 f1 = *(const float4*)(s + 4);
  float4 f2 = *(const float4*)(s + 8);
  float4 f3 = *(const float4*)(s + 12);
  short8 v0, v1;
  v0[0] = (short)f2bf(f0.x); v0[1] = (short)f2bf(f0.y);
  v0[2] = (short)f2bf(f0.z); v0[3] = (short)f2bf(f0.w);
  v0[4] = (short)f2bf(f1.x); v0[5] = (short)f2bf(f1.y);
  v0[6] = (short)f2bf(f1.z); v0[7] = (short)f2bf(f1.w);
  v1[0] = (short)f2bf(f2.x); v1[1] = (short)f2bf(f2.y);
  v1[2] = (short)f2bf(f2.z); v1[3] = (short)f2bf(f2.w);
  v1[4] = (short)f2bf(f3.x); v1[5] = (short)f2bf(f3.y);
  v1[6] = (short)f2bf(f3.z); v1[7] = (short)f2bf(f3.w);
  *(short8*)(Alds + r * 144 + cq * 32)      = v0;
  *(short8*)(Alds + r * 144 + cq * 32 + 16) = v1;
}

// One BK=64 K-step of the projection GEMM, wave tile 64(M) x 64(N).
static __device__ __forceinline__ void gemm_step(f32x4 acc[4][4], const char* Alds,
                                                 const char* Blds, int w, int lane) {
  const int lr = lane & 15, lk = lane >> 4;
#pragma unroll
  for (int s = 0; s < 2; ++s) {
    short8 a[4], b[4];
#pragma unroll
    for (int mt = 0; mt < 4; ++mt)
      a[mt] = *(const short8*)(Alds + (mt * 16 + lr) * 144 + s * 64 + lk * 16);
#pragma unroll
    for (int nt = 0; nt < 4; ++nt) {
      const int nf = w * 64 + nt * 16 + lr;
      b[nt] = *(const short8*)(Blds + (size_t)nf * 128 + ((s * 64 + lk * 16) ^ ((nf & 7) << 4)));
    }
#pragma unroll
    for (int mt = 0; mt < 4; ++mt)
#pragma unroll
      for (int nt = 0; nt < 4; ++nt)
        acc[mt][nt] = MFMA(a[mt], b[nt], acc[mt][nt]);
  }
}

// Per-row LayerNorm over the wave's 64-col chunk (cols = nt*16 + lane&15 within chunk).
static __device__ __forceinline__ void chunk_layernorm(f32x4 acc[4][4], const float* sc,
                                                       const float* bs, int lane) {
  const int lr = lane & 15;
  float scl[4], bia[4];
#pragma unroll
  for (int nt = 0; nt < 4; ++nt) { scl[nt] = sc[nt * 16 + lr]; bia[nt] = bs[nt * 16 + lr]; }
#pragma unroll
  for (int mt = 0; mt < 4; ++mt) {
#pragma unroll
    for (int j = 0; j < 4; ++j) {
      float a0 = acc[mt][0][j], a1 = acc[mt][1][j], a2 = acc[mt][2][j], a3 = acc[mt][3][j];
      float s  = a0 + a1 + a2 + a3;
      float s2 = a0 * a0 + a1 * a1 + a2 * a2 + a3 * a3;
#pragma unroll
      for (int off = 1; off < 16; off <<= 1) {
        s  += __shfl_xor(s, off, 16);
        s2 += __shfl_xor(s2, off, 16);
      }
      const float mu  = s * (1.0f / 64.0f);
      const float var = s2 * (1.0f / 64.0f) - mu * mu;
      const float rs  = rsqrtf(var + EPS);
#pragma unroll
      for (int nt = 0; nt < 4; ++nt)
        acc[mt][nt][j] = (acc[mt][nt][j] - mu) * rs * scl[nt] + bia[nt];
    }
  }
}

// ---------------- kernel 1: weight transpose/cast prep ----------------
// Wt[f][k] = W[k][f]; Vt additionally scaled by exp(log_scale[f]).
__global__ void prep_weights_kernel(const float* __restrict__ Q, const float* __restrict__ K,
                                    const float* __restrict__ V, const float* __restrict__ ls,
                                    unsigned short* __restrict__ Qt, unsigned short* __restrict__ Kt,
                                    unsigned short* __restrict__ Vt) {
  const int flat = blockIdx.x * 256 + threadIdx.x;  // < 3*131072
  const int mat = flat >> 17;
  const int rem = flat & 131071;
  const int f = rem & 511;
  const int k = rem >> 9;
  if (mat == 0)      Qt[f * 256 + k] = f2bf(Q[k * 512 + f]);
  else if (mat == 1) Kt[f * 256 + k] = f2bf(K[k * 512 + f]);
  else               Vt[f * 256 + k] = f2bf(V[k * 512 + f] * expf(ls[f]));
}

// ---------------- kernel 2: kv projections + LN + partial ctx ----------------
// grid 1024: rb = bid>>1 (64-row tile), nb = bid&1 (256-feature half).
__launch_bounds__(256, 2)
__global__ void kv_ctx_kernel(const float* __restrict__ kv,
                              const unsigned short* __restrict__ Kt,
                              const unsigned short* __restrict__ Vt,
                              const float* __restrict__ lnk_s, const float* __restrict__ lnk_b,
                              const float* __restrict__ lnv_s, const float* __restrict__ lnv_b,
                              float* __restrict__ partials) {
  __shared__ __align__(16) char smem[41984];
  char* Alds = smem;            // phase1: [64][72] bf16
  char* Blds = smem + 9216;     // phase1: [256][64] bf16 linear (src-preswizzled)
  char* knT  = smem;            // phase2: [64 d][128 t] bf16, 256B rows, xor-swz
  char* vnT  = smem + 16384;    // phase2: [64 e][128 t] bf16

  const int tid = threadIdx.x, lane = tid & 63, w = tid >> 6;
  const int bid = blockIdx.x, rb = bid >> 1, nb = bid & 1;
  const int row0 = rb * 64;
  const int lr = lane & 15, lk = lane >> 4;

  const f32x4 z4 = {0.f, 0.f, 0.f, 0.f};
  f32x4 acck[4][4], accv[4][4];
#pragma unroll
  for (int i = 0; i < 4; ++i)
#pragma unroll
    for (int j = 0; j < 4; ++j) { acck[i][j] = z4; accv[i][j] = z4; }

  const float* arows = kv + (size_t)row0 * XDIM;
  const unsigned short* ktp = Kt + (size_t)(nb * 256) * 256;
  const unsigned short* vtp = Vt + (size_t)(nb * 256) * 256;

  for (int ks = 0; ks < 4; ++ks) {
    stage_a(arows, ks, tid, Alds);
    stage_wpanel(ktp, ks, w, lane, Blds);
    __syncthreads();
    gemm_step(acck, Alds, Blds, w, lane);
    __syncthreads();
    stage_wpanel(vtp, ks, w, lane, Blds);
    __syncthreads();
    gemm_step(accv, Alds, Blds, w, lane);
    __syncthreads();
  }

  chunk_layernorm(acck, lnk_s, lnk_b, lane);
  chunk_layernorm(accv, lnv_s, lnv_b, lane);

  // ---- ctx phase: ctx[d][e] += sum_t knT[d][t]*vn[t][e], t = chunk*64 + local_row ----
  f32x4 cacc[4];
#pragma unroll
  for (int i = 0; i < 4; ++i) cacc[i] = z4;

#pragma unroll
  for (int half = 0; half < 2; ++half) {
    if ((w >> 1) == half) {  // waves holding chunks {2*half, 2*half+1} write this t-half
      const int tbase = (w & 1) * 64;
#pragma unroll
      for (int mt = 0; mt < 4; ++mt)
#pragma unroll
        for (int j = 0; j < 4; ++j) {
          const int tt = tbase + mt * 16 + lk * 4 + j;
#pragma unroll
          for (int nt = 0; nt < 4; ++nt) {
            const int d = nt * 16 + lr;
            const int boff = d * 256 + ((tt * 2) ^ ((d & 7) << 4));
            *(unsigned short*)(knT + boff) = f2bf(acck[mt][nt][j]);
            *(unsigned short*)(vnT + boff) = f2bf(accv[mt][nt][j]);
          }
        }
    }
    __syncthreads();
    const int drow = w * 16 + lr;  // wave owns ctx rows [w*16, w*16+16)
#pragma unroll
    for (int s = 0; s < 4; ++s) {
      const short8 a = *(const short8*)(knT + drow * 256 + ((s * 64 + lk * 16) ^ ((drow & 7) << 4)));
#pragma unroll
      for (int nt = 0; nt < 4; ++nt) {
        const int e = nt * 16 + lr;
        const short8 b = *(const short8*)(vnT + e * 256 + ((s * 64 + lk * 16) ^ ((e & 7) << 4)));
        cacc[nt] = MFMA(a, b, cacc[nt]);
      }
    }
    __syncthreads();
  }

  float* pout = partials + (size_t)bid * 4096;
#pragma unroll
  for (int nt = 0; nt < 4; ++nt)
#pragma unroll
    for (int j = 0; j < 4; ++j) {
      const int d = w * 16 + lk * 4 + j;
      const int e = nt * 16 + lr;
      pout[d * 64 + e] = cacc[nt][j];
    }
}

// ---------------- kernel 3: reduce partials -> ctxT (bf16, /8192, transposed) ----------------
// grid 256: gg = bid>>3 (group), sl = bid&7 (512-cell slice)
__global__ void reduce_ctx_kernel(const float* __restrict__ partials,
                                  unsigned short* __restrict__ ctxTg) {
  const int bid = blockIdx.x, t = threadIdx.x;
  const int gg = bid >> 3, sl = bid & 7;
  const float* base = partials + (size_t)gg * 32 * 4096;
#pragma unroll
  for (int rep = 0; rep < 2; ++rep) {
    const int idx = sl * 512 + rep * 256 + t;  // idx = d*64 + e
    float acc = 0.f;
#pragma unroll 8
    for (int p = 0; p < 32; ++p) acc += base[(size_t)p * 4096 + idx];
    const int d = idx >> 6, e = idx & 63;
    ctxTg[(size_t)gg * 4096 + e * 64 + d] = f2bf(acc * (1.0f / 8192.0f));
  }
}

// ---------------- kernel 4: q projection + LN + out = qn @ ctx ----------------
__launch_bounds__(256, 2)
__global__ void q_out_kernel(const float* __restrict__ x, const unsigned short* __restrict__ Qt,
                             const unsigned short* __restrict__ ctxTg,
                             const float* __restrict__ lnq_s, const float* __restrict__ lnq_b,
                             float* __restrict__ out) {
  __shared__ __align__(16) char smem[41984];
  char* Alds = smem;
  char* Blds = smem + 9216;
  char* ctxT = smem;            // phase2: [64 e][72] bf16 padded (144 B rows)
  char* A2   = smem + 9216;     // phase2: [256 m][64 d] bf16, 128 B rows, xor-swz

  const int tid = threadIdx.x, lane = tid & 63, w = tid >> 6;
  const int bid = blockIdx.x, rb = bid >> 1, nb = bid & 1;
  const int row0 = rb * 64;
  const int g = row0 >> 10;     // = b*8 + h
  const int lr = lane & 15, lk = lane >> 4;

  const f32x4 z4 = {0.f, 0.f, 0.f, 0.f};
  f32x4 acc[4][4];
#pragma unroll
  for (int i = 0; i < 4; ++i)
#pragma unroll
    for (int j = 0; j < 4; ++j) acc[i][j] = z4;

  const float* arows = x + (size_t)row0 * XDIM;
  const unsigned short* qtp = Qt + (size_t)(nb * 256) * 256;

  for (int ks = 0; ks < 4; ++ks) {
    stage_a(arows, ks, tid, Alds);
    stage_wpanel(qtp, ks, w, lane, Blds);
    __syncthreads();
    gemm_step(acc, Alds, Blds, w, lane);
    __syncthreads();
  }

  chunk_layernorm(acc, lnq_s, lnq_b, lane);

  // stage ctxT for this group (into Alds region; phase1 done)
  {
    const unsigned short* src = ctxTg + (size_t)g * 4096 + (tid >> 2) * 64 + (tid & 3) * 16;
    short8 c0 = *(const short8*)(src);
    short8 c1 = *(const short8*)(src + 8);
    char* dst = ctxT + (tid >> 2) * 144 + (tid & 3) * 32;
    *(short8*)dst        = c0;
    *(short8*)(dst + 16) = c1;
  }

  // write qn into A2: m = chunk_local*64 + local_row, chunk_local = w
#pragma unroll
  for (int mt = 0; mt < 4; ++mt)
#pragma unroll
    for (int j = 0; j < 4; ++j) {
      const int m = w * 64 + mt * 16 + lk * 4 + j;
#pragma unroll
      for (int nt = 0; nt < 4; ++nt) {
        const int d = nt * 16 + lr;
        *(unsigned short*)(A2 + (size_t)m * 128 + ((d * 2) ^ ((m & 7) << 4))) = f2bf(acc[mt][nt][j]);
      }
    }
  __syncthreads();

  // out MFMA: wave handles m in [w*64, w*64+64): out[m][e] = sum_d qn[m][d]*ctx[d][e]
  f32x4 o[4][4];
#pragma unroll
  for (int i = 0; i < 4; ++i)
#pragma unroll
    for (int j = 0; j < 4; ++j) o[i][j] = z4;

#pragma unroll
  for (int s = 0; s < 2; ++s) {
    short8 a[4], b[4];
#pragma unroll
    for (int mt = 0; mt < 4; ++mt) {
      const int m = w * 64 + mt * 16 + lr;
      a[mt] = *(const short8*)(A2 + (size_t)m * 128 + ((s * 64 + lk * 16) ^ ((m & 7) << 4)));
    }
#pragma unroll
    for (int nt = 0; nt < 4; ++nt) {
      const int e = nt * 16 + lr;
      b[nt] = *(const short8*)(ctxT + e * 144 + s * 64 + lk * 16);
    }
#pragma unroll
    for (int mt = 0; mt < 4; ++mt)
#pragma unroll
      for (int nt = 0; nt < 4; ++nt)
        o[mt][nt] = MFMA(a[mt], b[nt], o[mt][nt]);
  }

  // store: row = row0 + (m&63), col = nb*256 + (m>>6)*64 + e
#pragma unroll
  for (int mt = 0; mt < 4; ++mt)
#pragma unroll
    for (int nt = 0; nt < 4; ++nt)
#pragma unroll
      for (int j = 0; j < 4; ++j) {
        const int m = w * 64 + mt * 16 + lk * 4 + j;
        const int col = nb * 256 + (m >> 6) * 64 + nt * 16 + lr;
        out[(size_t)(row0 + (m & 63)) * FDIM + col] = o[mt][nt][j];
      }
}

// ---------------- launch ----------------
extern "C" void kernel_launch(void* const* d_in, const int* in_sizes, int n_in,
                              void* d_out, int out_size, void* d_ws, size_t ws_size,
                              hipStream_t stream) {
  (void)in_sizes; (void)n_in; (void)out_size; (void)ws_size;
  const float* x     = (const float*)d_in[0];
  const float* kv    = (const float*)d_in[1];
  const float* Q     = (const float*)d_in[2];
  const float* K     = (const float*)d_in[3];
  const float* V     = (const float*)d_in[4];
  const float* ls    = (const float*)d_in[5];
  const float* lnq_s = (const float*)d_in[6];
  const float* lnq_b = (const float*)d_in[7];
  const float* lnk_s = (const float*)d_in[8];
  const float* lnk_b = (const float*)d_in[9];
  const float* lnv_s = (const float*)d_in[10];
  const float* lnv_b = (const float*)d_in[11];
  float* out = (float*)d_out;

  char* ws = (char*)d_ws;
  unsigned short* Qt   = (unsigned short*)(ws + QT_OFF);
  unsigned short* Kt   = (unsigned short*)(ws + KT_OFF);
  unsigned short* Vt   = (unsigned short*)(ws + VT_OFF);
  unsigned short* ctxT = (unsigned short*)(ws + CTXT_OFF);
  float* partials      = (float*)(ws + PART_OFF);

  prep_weights_kernel<<<1536, 256, 0, stream>>>(Q, K, V, ls, Qt, Kt, Vt);
  kv_ctx_kernel<<<1024, 256, 0, stream>>>(kv, Kt, Vt, lnk_s, lnk_b, lnv_s, lnv_b, partials);
  reduce_ctx_kernel<<<256, 256, 0, stream>>>(partials, ctxT);
  q_out_kernel<<<1024, 256, 0, stream>>>(x, Qt, ctxT, lnq_s, lnq_b, out);
}